// Round 5
// baseline (396.389 us; speedup 1.0000x reference)
//
#include <hip/hip_runtime.h>

#define HSZ 50
#define TSZ 512

typedef _Float16 half2_t __attribute__((ext_vector_type(2)));

// sigmoid(x) = 1/(1+exp(-x)); robust at extremes (exp->inf => 0, exp->0 => 1)
__device__ __forceinline__ float fast_sig(float x) {
    return __builtin_amdgcn_rcpf(1.0f + __expf(-x));
}
// tanh(x) = 1 - 2/(exp(2x)+1); robust at extremes (exp->inf => 1, exp->0 => -1)
__device__ __forceinline__ float fast_tanh(float x) {
    return fmaf(-2.0f, __builtin_amdgcn_rcpf(1.0f + __expf(2.0f * x)), 1.0f);
}

// Neighbor value across lane^1 via DPP quad_perm [1,0,3,2] (pure VALU).
__device__ __forceinline__ float nbr_xor1(float v) {
    return __int_as_float(__builtin_amdgcn_update_dpp(
        0, __float_as_int(v), 0xB1, 0xF, 0xF, true));
}

__device__ __forceinline__ half2_t u_as_h2(unsigned u) {
    union { unsigned u; half2_t h; } c; c.u = u; return c.h;
}
__device__ __forceinline__ unsigned h2_as_u(half2_t h) {
    union { half2_t h; unsigned u; } c; c.h = h; return c.u;
}

// One wave per batch element; lane j<50 owns hidden unit j and its 4 gate rows
// of W_hh as packed half2 (4*25 = 100 VGPRs). Matvec = v_dot2_f32_f16
// (2 MACs/instr, fp32 accumulate); h broadcast by 25 v_readlane of a packed
// {h_2m, h_2m+1} dword. Register-only recurrence: no LDS, no barriers.
//
// amdgpu_waves_per_eu(2,2): pins the RA occupancy target to exactly 2
// waves/EU (all this 2048-wave grid can use), giving a 256-reg arch-VGPR
// budget. Without the max bound, RA targets high occupancy and shoves the
// weight array into AGPRs, paying a v_accvgpr_read per weight per timestep
// (~200 extra instrs/step -- the R1/R2/R4 plateau at ~400 us).
__global__ __launch_bounds__(256) __attribute__((amdgpu_waves_per_eu(2, 2)))
void lstm_fused(const float* __restrict__ x,
                const float* __restrict__ W_ih,
                const float* __restrict__ W_hh,
                const float* __restrict__ b_ih,
                const float* __restrict__ b_hh,
                const float* __restrict__ W_lin,
                const float* __restrict__ b_lin,
                float* __restrict__ out)
{
    __shared__ float xs[4 * TSZ];     // staged x for this block's 4 batches

    const int tid = threadIdx.x;
    const int w   = tid >> 6;         // wave id within block (0..3)
    const int j   = tid & 63;         // lane id
    const int b   = blockIdx.x * 4 + w;

    // Coalesced stage of x[b0..b0+3][0..T): block-flat layout matches global.
    const float* xg = x + (size_t)blockIdx.x * 4 * TSZ;
    for (int idx = tid; idx < 4 * TSZ; idx += 256)
        xs[idx] = xg[idx];

    const bool active = (j < HSZ);
    const int  jj     = active ? j : 0;   // clamp: inactive lanes run unit 0's
                                          // bounded dynamics; never read back.

    // Weights as packed half2 (RNE device converts). 100 VGPRs total.
    half2_t w2[4][25];
    float   wih[4], bias[4];
#pragma unroll
    for (int g = 0; g < 4; ++g) {
        const int row = g * HSZ + jj;                  // PyTorch order i,f,g,o
        const float2* rp = (const float2*)(W_hh + row * HSZ);   // 8B-aligned
#pragma unroll
        for (int p = 0; p < 25; ++p) {
            float2 v = rp[p];
            w2[g][p] = half2_t{(_Float16)v.x, (_Float16)v.y};
        }
        wih[g]  = W_ih[row];
        bias[g] = b_ih[row] + b_hh[row];
    }

    float h = 0.0f, c = 0.0f;
    __syncthreads();                  // xs ready
    const float* xw = &xs[w * TSZ];

#pragma unroll 1
    for (int t = 0; t < TSZ; ++t) {
        const float xv = xw[t];       // issued early, consumed after the dots

        // Pack {h_j, h_{j^1}} -> even lane 2m holds {h_2m, h_2m+1}.
        const float hn = nbr_xor1(h);
        const unsigned hpk = h2_as_u(half2_t{(_Float16)h, (_Float16)hn});

        // Two fp32 dot2 chains per gate (8 independent chains).
        float a0[4], a1[4];
#pragma unroll
        for (int g = 0; g < 4; ++g) { a0[g] = fmaf(xv, wih[g], bias[g]); a1[g] = 0.0f; }

#pragma unroll
        for (int p = 0; p < 25; ++p) {
            const half2_t hb = u_as_h2(
                (unsigned)__builtin_amdgcn_readlane((int)hpk, 2 * p));
            if (p & 1) {
#pragma unroll
                for (int g = 0; g < 4; ++g)
                    a1[g] = __builtin_amdgcn_fdot2(w2[g][p], hb, a1[g], false);
            } else {
#pragma unroll
                for (int g = 0; g < 4; ++g)
                    a0[g] = __builtin_amdgcn_fdot2(w2[g][p], hb, a0[g], false);
            }
        }

        const float gi = fast_sig (a0[0] + a1[0]);
        const float gf = fast_sig (a0[1] + a1[1]);
        const float gg = fast_tanh(a0[2] + a1[2]);
        const float go = fast_sig (a0[3] + a1[3]);
        c = fmaf(gf, c, gi * gg);
        h = go * fast_tanh(c);
    }

    // out[b] = dot(h_T, W_lin) + b_lin  (inactive lanes masked via wl = 0;
    // their h is bounded -- clamped-row dynamics -- so no NaN risk)
    const float wl = active ? W_lin[j] : 0.0f;
    float p = h * wl;
#pragma unroll
    for (int off = 32; off > 0; off >>= 1)
        p += __shfl_down(p, off, 64);
    if (j == 0) out[b] = p + b_lin[0];
}

extern "C" void kernel_launch(void* const* d_in, const int* in_sizes, int n_in,
                              void* d_out, int out_size, void* d_ws, size_t ws_size,
                              hipStream_t stream) {
    const float* x     = (const float*)d_in[0];
    const float* W_ih  = (const float*)d_in[1];
    const float* W_hh  = (const float*)d_in[2];
    const float* b_ih  = (const float*)d_in[3];
    const float* b_hh  = (const float*)d_in[4];
    const float* W_lin = (const float*)d_in[5];
    const float* b_lin = (const float*)d_in[6];
    float* outp = (float*)d_out;

    const int B = in_sizes[0] / TSZ;   // 2048 for this problem (divisible by 4)
    hipLaunchKernelGGL(lstm_fused, dim3(B / 4), dim3(256), 0, stream,
                       x, W_ih, W_hh, b_ih, b_hh, W_lin, b_lin, outp);
}

// Round 6
// 328.286 us; speedup vs baseline: 1.2074x; 1.2074x over previous
//
#include <hip/hip_runtime.h>

#define HSZ 50        // real hidden units
#define TSZ 512       // timesteps
#define NB  16        // batch tile per workgroup
#define KPAD 72       // padded f16 h-row length (144 B -> bank-conflict-free-ish)

typedef _Float16 half8  __attribute__((ext_vector_type(8)));
typedef float    floatx4 __attribute__((ext_vector_type(4)));

// sigmoid/tanh via exp+rcp, robust at extremes (proven in R4/R5, absmax 9.8e-4)
__device__ __forceinline__ float fast_sig(float x) {
    return __builtin_amdgcn_rcpf(1.0f + __expf(-x));
}
__device__ __forceinline__ float fast_tanh(float x) {
    return fmaf(-2.0f, __builtin_amdgcn_rcpf(1.0f + __expf(2.0f * x)), 1.0f);
}

// Workgroup = 4 waves = one 16-batch tile. Units padded 50->64; wave w owns
// units [16w, 16w+16) and computes their i,f,g,o gate tiles with
// mfma_f32_16x16x32_f16 (f16 inputs, fp32 accumulate). C-layout
// (row=(lane>>4)*4+reg = unit, col=lane&15 = batch) puts i,f,g,o for 4 units
// x 1 batch in each lane -> activations and c/h state are lane-local.
// h is exchanged as transposed f16 rows h^T[batch][k] in LDS (the proven
// B^T k-contiguous fragment pattern), double-buffered, 1 barrier/step.
// Padded units have zero weights/bias -> their h stays exactly 0.
__global__ __launch_bounds__(256) __attribute__((amdgpu_waves_per_eu(1, 1)))
void lstm_mfma(const float* __restrict__ x,
               const float* __restrict__ W_ih,
               const float* __restrict__ W_hh,
               const float* __restrict__ b_ih,
               const float* __restrict__ b_hh,
               const float* __restrict__ W_lin,
               const float* __restrict__ b_lin,
               float* __restrict__ out)
{
    __shared__ float xs[TSZ][NB];                        // x transposed [t][n]
    __shared__ __align__(16) _Float16 hlds[2][NB][KPAD]; // h^T double buffer

    const int tid = threadIdx.x;
    const int w   = tid >> 6;        // wave id (0..3) -> unit group
    const int ln  = tid & 63;        // lane
    const int n   = ln & 15;         // batch column (C col / B col / x col)
    const int q   = ln >> 4;         // quad (0..3)

    // --- stage x transposed: global [b][t] -> LDS [t][b] (coalesced reads) ---
    const float* xg = x + (size_t)blockIdx.x * NB * TSZ;
    for (int i = tid; i < NB * TSZ; i += 256) {
        const int bl = i >> 9;               // i / TSZ
        const int t  = i & (TSZ - 1);
        xs[t][bl] = xg[i];
    }
    // --- zero both h buffers (h0 = 0; also the k>=50 pad stays 0 forever) ---
    for (int i = tid; i < 2 * NB * KPAD; i += 256)
        ((_Float16*)hlds)[i] = (_Float16)0.0f;

    // --- A fragments: W_hh rows for this wave's units, f16, in registers.
    //     A-frag layout: lane holds A[m=lane&15][k = kt*32 + q*8 + j], j=0..7.
    const int uA = 16 * w + n;               // m-index unit for A fragments
    half8 afrag[4][2];
#pragma unroll
    for (int g = 0; g < 4; ++g) {
#pragma unroll
        for (int kt = 0; kt < 2; ++kt) {
#pragma unroll
            for (int j = 0; j < 8; ++j) {
                const int k = kt * 32 + q * 8 + j;
                const float v = (uA < HSZ && k < HSZ)
                              ? W_hh[(g * HSZ + uA) * HSZ + k] : 0.0f;
                afrag[g][kt][j] = (_Float16)v;
            }
        }
    }
    // --- bias / W_ih for this lane's C rows: units ub..ub+3 ---
    const int ub = 16 * w + q * 4;
    float biasr[4][4], wihr[4][4];
#pragma unroll
    for (int g = 0; g < 4; ++g) {
#pragma unroll
        for (int r = 0; r < 4; ++r) {
            const int u   = ub + r;
            const int row = g * HSZ + u;
            const bool ok = (u < HSZ);
            biasr[g][r] = ok ? (b_ih[row] + b_hh[row]) : 0.0f;
            wihr[g][r]  = ok ? W_ih[row] : 0.0f;
        }
    }

    float cc[4] = {0.0f, 0.0f, 0.0f, 0.0f};   // cell state, lane's 4 units
    __syncthreads();                           // xs + hlds ready

#pragma unroll 2
    for (int t = 0; t < TSZ; ++t) {
        const int rb = t & 1, wb = rb ^ 1;

        // B fragments: B[k = kt*32 + q*8 + j][n] = hlds[rb][n][k-contiguous]
        const half8 bf0 = *(const half8*)&hlds[rb][n][q * 8];
        const half8 bf1 = *(const half8*)&hlds[rb][n][32 + q * 8];
        const float xv  = xs[t][n];

        // Accumulators init with bias + x-projection (fp32, C layout).
        floatx4 acc[4];
#pragma unroll
        for (int g = 0; g < 4; ++g) {
#pragma unroll
            for (int r = 0; r < 4; ++r)
                acc[g][r] = fmaf(xv, wihr[g][r], biasr[g][r]);
        }
#pragma unroll
        for (int g = 0; g < 4; ++g) {
            acc[g] = __builtin_amdgcn_mfma_f32_16x16x32_f16(afrag[g][0], bf0, acc[g], 0, 0, 0);
            acc[g] = __builtin_amdgcn_mfma_f32_16x16x32_f16(afrag[g][1], bf1, acc[g], 0, 0, 0);
        }

        // Lane-local activations + state update for 4 units x 1 batch.
#pragma unroll
        for (int r = 0; r < 4; ++r) {
            const float gi = fast_sig (acc[0][r]);
            const float gf = fast_sig (acc[1][r]);
            const float gg = fast_tanh(acc[2][r]);
            const float go = fast_sig (acc[3][r]);
            cc[r] = fmaf(gf, cc[r], gi * gg);
            const float h = go * fast_tanh(cc[r]);
            hlds[wb][n][ub + r] = (_Float16)h;   // consecutive -> merged store
        }
        __syncthreads();   // h(t) visible to all waves before next B-read
    }

    // --- epilogue: out[n] = b_lin + sum_u h_T[u]*W_lin[u], wave 0 only.
    //     Final h is in buffer (TSZ & 1) ^ 1 ... TSZ even -> buffer 0.
    if (w == 0 && ln < NB) {
        float acc = b_lin[0];
        for (int u = 0; u < HSZ; ++u)
            acc = fmaf((float)hlds[0][ln][u], W_lin[u], acc);
        out[(size_t)blockIdx.x * NB + ln] = acc;
    }
}

extern "C" void kernel_launch(void* const* d_in, const int* in_sizes, int n_in,
                              void* d_out, int out_size, void* d_ws, size_t ws_size,
                              hipStream_t stream) {
    const float* x     = (const float*)d_in[0];
    const float* W_ih  = (const float*)d_in[1];
    const float* W_hh  = (const float*)d_in[2];
    const float* b_ih  = (const float*)d_in[3];
    const float* b_hh  = (const float*)d_in[4];
    const float* W_lin = (const float*)d_in[5];
    const float* b_lin = (const float*)d_in[6];
    float* outp = (float*)d_out;

    const int B = in_sizes[0] / TSZ;   // 2048 -> 128 workgroups of 16 batches
    hipLaunchKernelGGL(lstm_mfma, dim3(B / NB), dim3(256), 0, stream,
                       x, W_ih, W_hh, b_ih, b_hh, W_lin, b_lin, outp);
}